// Round 8
// baseline (200.708 us; speedup 1.0000x reference)
//
#include <hip/hip_runtime.h>
#include <math.h>

#define B_ 2
#define S_ 2048
#define E_ 1024
#define H_ 16
#define D_ 64
#define M_ (B_*S_)   // 4096 rows

typedef _Float16 f16x8  __attribute__((ext_vector_type(8)));
typedef _Float16 f16x4v __attribute__((ext_vector_type(4)));
typedef __fp16   h16x2  __attribute__((ext_vector_type(2)));
typedef float    f32x4  __attribute__((ext_vector_type(4)));

__device__ __forceinline__ ushort f2h(float f) {
    _Float16 h = (_Float16)f;               // RNE
    return __builtin_bit_cast(ushort, h);
}

// async global->LDS, 16B per lane; LDS dest = wave-uniform base + lane*16.
// NOTE (R5 post-mortem): the builtin's imm-offset arg applies to BOTH the
// global and LDS addresses — do not use it for "global-only" offsets.
__device__ __forceinline__ void gload_lds16(const ushort* g, ushort* l) {
    __builtin_amdgcn_global_load_lds(
        (const __attribute__((address_space(1))) unsigned int*)g,
        (__attribute__((address_space(3))) unsigned int*)l, 16, 0, 0);
}

// 2^x via v_exp_f32 (avoid __exp2f: glibc reserves that name)
__device__ __forceinline__ float exp2_fast(float x) {
    return __builtin_amdgcn_exp2f(x);
}

// ---------------- fused prep: W transpose+cast | x cast | RoPE table --------
__global__ void prep_kernel(const float* __restrict__ x,
                            const float* __restrict__ W0, const float* __restrict__ W1,
                            const float* __restrict__ W2, const float* __restrict__ W3,
                            ushort* __restrict__ xf, ushort* __restrict__ WT,
                            float* __restrict__ ct, float* __restrict__ st)
{
    const int bid = blockIdx.x;
    const int tid = threadIdx.x;
    __shared__ float tile[32][33];

    if (bid < 2048) {                       // ---- W transpose + f16 cast ----
        const int z = bid >> 9, rem = bid & 511;
        const int kp = rem >> 5, nb = (rem & 31) * 32;
        const float* W = (z == 0) ? W0 : (z == 1) ? W1 : (z == 2) ? W2 : W3;
        const size_t zoff = (size_t)z * E_ * E_;
        const int tx = tid & 31, ty = tid >> 5;   // 32 x 8
        #pragma unroll
        for (int kk = 0; kk < 2; kk++) {
            const int k0 = kp * 64 + kk * 32;
            #pragma unroll
            for (int i = 0; i < 4; i++) {
                int r = i * 8 + ty;
                tile[r][tx] = W[(size_t)(k0 + r) * E_ + nb + tx];
            }
            __syncthreads();
            #pragma unroll
            for (int i = 0; i < 4; i++) {
                int r = i * 8 + ty;                 // local n
                WT[zoff + (size_t)(nb + r) * E_ + k0 + tx] = f2h(tile[tx][r]);
            }
            __syncthreads();
        }
    } else if (bid < 3072) {                // ---- x fp32 -> f16 ----
        const int base = (bid - 2048) * 4096 + tid * 4;
        #pragma unroll
        for (int j = 0; j < 4; j++) {
            const int i = base + j * 1024;
            float4 v = *(const float4*)&x[i];
            *(ushort4*)&xf[i] = make_ushort4(f2h(v.x), f2h(v.y), f2h(v.z), f2h(v.w));
        }
    } else {                                // ---- RoPE cos/sin table ----
        const int i = (bid - 3072) * 256 + tid;   // < S_*32
        const int j = i & 31, pos = i >> 5;
        float invf = (float)pow(10000.0, -(double)j / 32.0);
        float ang  = (float)pos * invf;
        ct[i] = (float)cos((double)ang);
        st[i] = (float)sin((double)ang);
    }
}

// ---------------- f16 MFMA GEMM: 3-buffer pipeline, raw-barrier K-loop ------
// modes: 0 = Q (bias+RoPE+0.125*log2e, f16, 16B-chunk XOR-swizzled cols),
//        1 = K (same swizzle, no scale),
//        2 = V (32-key-group strips with k-slot permutation + octet swizzle)
#define GBM 128
#define GBN 128
#define GBK 32
#define LOG2E 1.44269504088896340736f

__global__ __launch_bounds__(256, 3)
void gemm_f16(const ushort* __restrict__ A, const ushort* __restrict__ WTp,
              const float* __restrict__ b0, const float* __restrict__ b1,
              const float* __restrict__ b2,
              const float* __restrict__ ct, const float* __restrict__ st,
              ushort* __restrict__ outQ, ushort* __restrict__ outK,
              ushort* __restrict__ outV)
{
    __shared__ __align__(16) ushort lA[3][GBM * GBK];   // [buf][r][k], unpadded (DMA contract)
    __shared__ __align__(16) ushort lB[3][GBN * GBK];   // W^T tile: [buf][n][k]

    const int tid  = threadIdx.x;
    const int wv   = tid >> 6, lane = tid & 63;
    const int c    = lane & 15, qd = lane >> 4;
    const int rh   = wv >> 1, chn = wv & 1;

    const int mode = (int)blockIdx.z;
    const size_t zoff = (size_t)blockIdx.z * (E_ * E_);
    const ushort* Bt = WTp + zoff;

    // XCD-aware flat mapping: same-m blocks land on the same XCD
    const int m0 = (blockIdx.x & 31) * GBM;
    const int n0 = (blockIdx.x >> 5) * GBN;

    const ushort* gsrc = (wv < 2) ? A : Bt;
    const int rowbase = ((wv < 2) ? m0 : n0) + (wv & 1) * 64;
    const int lofs = (wv & 1) * 64 * GBK;
    const int srow = lane >> 2;
    const int soct = (lane & 3) * 8;

    f32x4 acc[4][4] = {};

    // ---- prologue: stage tiles 0 and 1 into buffers 0 and 1 ----
    #pragma unroll
    for (int pt = 0; pt < 2; pt++) {
        ushort* dst = ((wv < 2) ? &lA[pt][0] : &lB[pt][0]) + lofs;
        const int k0i = pt * GBK;
        #pragma unroll
        for (int cc = 0; cc < 4; cc++) {
            const ushort* g = gsrc + (size_t)(rowbase + cc * 16 + srow) * E_ + k0i + soct;
            gload_lds16(g, dst + cc * 512);
        }
    }
    __builtin_amdgcn_s_waitcnt(0x0F74);   // vmcnt(4): tile0 landed, tile1 flying
    __builtin_amdgcn_s_barrier();

    for (int t = 0; t < E_ / GBK; t++) {
        // ---- issue tile t+2's DMA (kept in flight across the barrier) ----
        if (t + 2 < E_ / GBK) {
            const int bi = (t + 2) % 3;
            const int k0i = (t + 2) * GBK;
            ushort* dst = ((wv < 2) ? &lA[bi][0] : &lB[bi][0]) + lofs;
            #pragma unroll
            for (int cc = 0; cc < 4; cc++) {
                const ushort* g = gsrc + (size_t)(rowbase + cc * 16 + srow) * E_ + k0i + soct;
                gload_lds16(g, dst + cc * 512);
            }
        }

        const ushort* Ab = lA[t % 3];
        const ushort* Bb = lB[t % 3];

        f16x8 af[4], bf[4];
        #pragma unroll
        for (int mt = 0; mt < 4; mt++)
            af[mt] = *(const f16x8*)&Ab[(rh * 64 + mt * 16 + c) * GBK + qd * 8];
        #pragma unroll
        for (int nt = 0; nt < 4; nt++)
            bf[nt] = *(const f16x8*)&Bb[(chn * 64 + nt * 16 + c) * GBK + qd * 8];
        #pragma unroll
        for (int mt = 0; mt < 4; mt++)
            #pragma unroll
            for (int nt = 0; nt < 4; nt++)
                acc[mt][nt] = __builtin_amdgcn_mfma_f32_16x16x32_f16(af[mt], bf[nt], acc[mt][nt], 0, 0, 0);

        // ---- publish t+1 without draining t+2 ----
        if (t < E_ / GBK - 2) {
            __builtin_amdgcn_s_waitcnt(0x0F74);   // vmcnt(4): t+1 landed
            __builtin_amdgcn_s_barrier();
        } else if (t == E_ / GBK - 2) {
            __builtin_amdgcn_s_waitcnt(0x0F70);   // vmcnt(0): last tile landed
            __builtin_amdgcn_s_barrier();
        }
    }

    const float* bias = (mode == 0) ? b0 : (mode == 1) ? b1 : b2;
    const int colbase = n0 + chn * 64;                // head-aligned (64)

    if (mode == 2) {
        // V strips: Vf[bh][g(64 groups of 32 keys)][d(64)][kslot(32)], 4KB/group.
        // kslot = q*8 + h*4 + j for key k32 = h*16+q*4+j; octet swz oct^((d>>2)&3).
        const int hd = colbase >> 6;
        const int xr = (c >> 2) & 3;              // (d>>2)&3 for d = nt*16+c
        #pragma unroll
        for (int mt = 0; mt < 4; mt++)
            #pragma unroll
            for (int r = 0; r < 4; r++) {
                const int row = m0 + rh * 64 + mt * 16 + qd * 4 + r;
                const int bb = row >> 11, sl = row & (S_ - 1);
                const int g  = sl >> 5, k32 = sl & 31;
                const int q2 = (k32 >> 2) & 3, kh = k32 >> 4, kj = k32 & 3;
                const size_t base = (size_t)(bb * H_ + hd) * (S_ * D_)
                                  + g * 2048 + ((q2 ^ xr) << 3) + kh * 4 + kj;
                #pragma unroll
                for (int nt = 0; nt < 4; nt++) {
                    const int d = nt * 16 + c;        // 0..63 within head
                    outV[base + (size_t)d * 32] = f2h(acc[mt][nt][r] + bias[colbase + d]);
                }
            }
    } else {
        // Q/K: RoPE pair (j, j+32); cols stored 16B-chunk-swizzled: ch' = ch ^ (row&7)
        ushort* O = (mode == 0) ? outQ : outK;
        const float sc = (mode == 0) ? 0.125f * LOG2E : 1.0f;   // exp2 path in attn
        #pragma unroll
        for (int mt = 0; mt < 4; mt++)
            #pragma unroll
            for (int r = 0; r < 4; r++) {
                const int row = m0 + rh * 64 + mt * 16 + qd * 4 + r;
                const int pos = row & (S_ - 1);
                const int sw = row & 7;
                #pragma unroll
                for (int p = 0; p < 2; p++) {
                    const int j32 = p * 16 + c;
                    const float cth = ct[pos * 32 + j32], sth = st[pos * 32 + j32];
                    const float v1 = acc[mt][p][r]     + bias[colbase + p * 16 + c];
                    const float v2 = acc[mt][p + 2][r] + bias[colbase + (p + 2) * 16 + c];
                    const float o1 = (v1 * cth - v2 * sth) * sc;   // col cd1
                    const float o2 = (v2 * cth + v1 * sth) * sc;   // col cd1+32
                    const int cd1 = p * 16 + c, cd2 = cd1 + 32;
                    O[(size_t)row * E_ + colbase + (((cd1 >> 3) ^ sw) * 8) + (cd1 & 7)] = f2h(o1);
                    O[(size_t)row * E_ + colbase + (((cd2 >> 3) ^ sw) * 8) + (cd2 & 7)] = f2h(o2);
                }
            }
    }
}

// ---------------- out-proj GEMM: 64x128 tiles, 512 blocks = 2/CU exact ------
__global__ __launch_bounds__(256, 3)
void gemm_proj(const ushort* __restrict__ A, const ushort* __restrict__ WTp,
               const float* __restrict__ bo, float* __restrict__ outF)
{
    __shared__ __align__(16) ushort lA[3][64 * GBK];    // 4KB per buf
    __shared__ __align__(16) ushort lB[3][GBN * GBK];   // 8KB per buf

    const int tid  = threadIdx.x;
    const int wv   = tid >> 6, lane = tid & 63;
    const int c    = lane & 15, qd = lane >> 4;

    const int m0 = (blockIdx.x & 63) * 64;
    const int n0 = (blockIdx.x >> 6) * GBN;

    const bool stager = (wv < 3);
    const ushort* gsrc = (wv == 0) ? A : WTp;
    const int rowbase = (wv == 0) ? m0 : (n0 + (wv - 1) * 64);
    const int lofs = (wv == 0) ? 0 : (wv - 1) * 64 * GBK;
    const int srow = lane >> 2;
    const int soct = (lane & 3) * 8;

    f32x4 acc[4][2] = {};

    #pragma unroll
    for (int pt = 0; pt < 2; pt++) {
        if (stager) {
            ushort* dst = ((wv == 0) ? &lA[pt][0] : &lB[pt][0]) + lofs;
            const int k0i = pt * GBK;
            #pragma unroll
            for (int cc = 0; cc < 4; cc++) {
                const ushort* g = gsrc + (size_t)(rowbase + cc * 16 + srow) * E_ + k0i + soct;
                gload_lds16(g, dst + cc * 512);
            }
        }
    }
    __builtin_amdgcn_s_waitcnt(0x0F74);   // vmcnt(4) (wave3: trivial)
    __builtin_amdgcn_s_barrier();

    for (int t = 0; t < E_ / GBK; t++) {
        if (t + 2 < E_ / GBK && stager) {
            const int bi = (t + 2) % 3;
            const int k0i = (t + 2) * GBK;
            ushort* dst = ((wv == 0) ? &lA[bi][0] : &lB[bi][0]) + lofs;
            #pragma unroll
            for (int cc = 0; cc < 4; cc++) {
                const ushort* g = gsrc + (size_t)(rowbase + cc * 16 + srow) * E_ + k0i + soct;
                gload_lds16(g, dst + cc * 512);
            }
        }

        const ushort* Ab = lA[t % 3];
        const ushort* Bb = lB[t % 3];

        f16x8 af[4], bf[2];
        #pragma unroll
        for (int mt = 0; mt < 4; mt++)
            af[mt] = *(const f16x8*)&Ab[(mt * 16 + c) * GBK + qd * 8];
        #pragma unroll
        for (int nt = 0; nt < 2; nt++)
            bf[nt] = *(const f16x8*)&Bb[(wv * 32 + nt * 16 + c) * GBK + qd * 8];
        #pragma unroll
        for (int mt = 0; mt < 4; mt++)
            #pragma unroll
            for (int nt = 0; nt < 2; nt++)
                acc[mt][nt] = __builtin_amdgcn_mfma_f32_16x16x32_f16(af[mt], bf[nt], acc[mt][nt], 0, 0, 0);

        if (t < E_ / GBK - 2) {
            __builtin_amdgcn_s_waitcnt(0x0F74);
            __builtin_amdgcn_s_barrier();
        } else if (t == E_ / GBK - 2) {
            __builtin_amdgcn_s_waitcnt(0x0F70);
            __builtin_amdgcn_s_barrier();
        }
    }

    #pragma unroll
    for (int mt = 0; mt < 4; mt++)
        #pragma unroll
        for (int r = 0; r < 4; r++) {
            const int row = m0 + mt * 16 + qd * 4 + r;
            #pragma unroll
            for (int nt = 0; nt < 2; nt++) {
                const int col = n0 + wv * 32 + nt * 16 + c;
                outF[(size_t)row * E_ + col] = acc[mt][nt][r] + bo[col];
            }
        }
}

// ---------------- MFMA flash attention: 32q blocks, 4 blocks/CU, no tail ----
// R8: R7's grid (1024 blocks @ 3/CU = 768 slots) ran in 2 ragged rounds
// (768+256) — avg ~8 waves/CU (OccupancyPercent 22% confirmed). This version
// halves the q-tile (32 rows/block, 4 waves x 4-way key split as before):
// acc 32 AGPR + ~62 arch VGPR ≈ 94 unified <= 128 cap, V single-buffered
// (issued post-PV behind sched_barrier; PV's ds_reads are lgkm-drained before
// its MFMAs, which precede the DMA issue -> no WAR) -> LDS 8KB/wave = 32KB.
// __launch_bounds__(256,4): 4 blocks/CU, 1024 slots; grid 2048 = exactly 2
// clean full rounds. vmcnt ladder: sub0 waits 6, sub1 waits 2 (drains V(T)
// en route), last iter 0.
__global__ __launch_bounds__(256, 4)
void attn_mfma(const ushort* __restrict__ Qf, const ushort* __restrict__ Kf,
               const ushort* __restrict__ Vfg, ushort* __restrict__ ctxf)
{
    __shared__ __align__(16) ushort L[16384];   // 32KB: 4 waves x (K 2x2KB | V 4KB)

    const int tid = threadIdx.x;
    const int wv = tid >> 6, lane = tid & 63;
    const int c = lane & 15, qd = lane >> 4;
    const int cs = c & 7;

    // XCD swizzle: 4 bh per XCD (2MB K/V < 4MB L2/XCD)
    const int xcd = blockIdx.x & 7, ii = blockIdx.x >> 3;
    const int bh = xcd * 4 + (ii & 3);
    const int qtb = ii >> 2;                // 0..63
    const int b = bh >> 4, h = bh & 15;
    const int q0 = qtb * 32;

    const size_t qrow0 = (size_t)b * S_ + q0;
    const size_t krow0 = (size_t)b * S_;
    const size_t vbase = (size_t)bh * (S_ * D_);

    const int l8 = lane >> 3, l7 = lane & 7;

    // ---- stage Q tile (32 rows, 4KB): 1 DMA per wave ----
    gload_lds16(Qf + (qrow0 + wv * 8 + l8) * E_ + h * 64 + l7 * 8, &L[wv * 512]);
    __syncthreads();
    f16x8 qfrag[2][2];
    #pragma unroll
    for (int qt = 0; qt < 2; qt++)
        #pragma unroll
        for (int kc = 0; kc < 2; kc++)
            qfrag[qt][kc] = *(const f16x8*)&L[(qt * 16 + c) * 64 + (((kc * 4 + qd) ^ cs) * 8)];
    __syncthreads();

    f32x4 acc[4][2] = {};          // [dt][qt]: O^T partial over this wave's keys
    float lsum[2] = {0.f, 0.f};

    ushort* const myL = &L[wv * 4096];      // K: [0|1024), [1024|2048); V: [2048,4096)
    const int vxo = (qd ^ ((c >> 2) & 3)) << 3;   // V octet swizzle (matches mode-2 store)

    // staging pointers (NEXT half-tile to stage); wave owns groups g = T*4+wv
    const ushort* kst0 = Kf + (krow0 + wv * 32 + l8) * E_ + h * 64 + l7 * 8;
    const ushort* kst1 = kst0 + 8 * E_;
    const ushort* vstA = Vfg + vbase + (size_t)wv * 2048 + lane * 8;
    const ushort* vstB = vstA + 512;

    // ---- prologue: K(0,h0) then V(0) full 4KB (queue order = steady state) --
    gload_lds16(kst0, myL);
    gload_lds16(kst1, myL + 512);
    kst0 += 16 * E_; kst1 += 16 * E_;
    gload_lds16(vstA, myL + 2048);
    gload_lds16(vstB, myL + 2560);
    vstA += 1024; vstB += 1024;
    gload_lds16(vstA, myL + 3072);
    gload_lds16(vstB, myL + 3584);
    vstA += 7168; vstB += 7168;

    #pragma unroll 1
    for (int T = 0; T < 16; T++) {
        uint4 bfu[2];                       // packed P (f16x8) per q-tile

        // ======== sub-iter 0: issue K(T,h1), QK over keys 0..15 ========
        {
            gload_lds16(kst0, myL + 1024);
            gload_lds16(kst1, myL + 1536);
            kst0 += 112 * E_; kst1 += 112 * E_;
            __builtin_amdgcn_s_waitcnt(0x0F76);   // vmcnt(6): K(T,h0) landed

            const ushort* kb = myL;               // K buf 0
            f16x8 kf0 = *(const f16x8*)&kb[c * 64 + ((qd ^ cs) * 8)];
            f16x8 kf1 = *(const f16x8*)&kb[c * 64 + (((4 + qd) ^ cs) * 8)];
            f32x4 sv[2];
            __builtin_amdgcn_s_setprio(1);
            #pragma unroll
            for (int qt = 0; qt < 2; qt++) {
                f32x4 s = {};
                s = __builtin_amdgcn_mfma_f32_16x16x32_f16(kf0, qfrag[qt][0], s, 0, 0, 0);
                sv[qt] = __builtin_amdgcn_mfma_f32_16x16x32_f16(kf1, qfrag[qt][1], s, 0, 0, 0);
            }
            __builtin_amdgcn_s_setprio(0);
            #pragma unroll
            for (int qt = 0; qt < 2; qt++) {
                const float p0 = exp2_fast(sv[qt][0]), p1 = exp2_fast(sv[qt][1]);
                const float p2 = exp2_fast(sv[qt][2]), p3 = exp2_fast(sv[qt][3]);
                lsum[qt] += (p0 + p1) + (p2 + p3);
                bfu[qt].x = __builtin_bit_cast(unsigned int, __builtin_amdgcn_cvt_pkrtz(p0, p1));
                bfu[qt].y = __builtin_bit_cast(unsigned int, __builtin_amdgcn_cvt_pkrtz(p2, p3));
            }
        }

        // ======== sub-iter 1: issue K(T+1,h0), QK over keys 16..31 ====
        {
            if (T < 15) {
                gload_lds16(kst0, myL);
                gload_lds16(kst1, myL + 512);
                kst0 += 16 * E_; kst1 += 16 * E_;
                __builtin_amdgcn_s_waitcnt(0x0F72);   // vmcnt(2): V(T)+K(T,h1) landed
            } else {
                __builtin_amdgcn_s_waitcnt(0x0F70);   // vmcnt(0): all landed
            }

            const ushort* kb = myL + 1024;            // K buf 1
            f16x8 kf0 = *(const f16x8*)&kb[c * 64 + ((qd ^ cs) * 8)];
            f16x8 kf1 = *(const f16x8*)&kb[c * 64 + (((4 + qd) ^ cs) * 8)];
            f32x4 sv[2];
            __builtin_amdgcn_s_setprio(1);
            #pragma unroll
            for (int qt = 0; qt < 2; qt++) {
                f32x4 s = {};
                s = __builtin_amdgcn_mfma_f32_16x16x32_f16(kf0, qfrag[qt][0], s, 0, 0, 0);
                sv[qt] = __builtin_amdgcn_mfma_f32_16x16x32_f16(kf1, qfrag[qt][1], s, 0, 0, 0);
            }
            __builtin_amdgcn_s_setprio(0);
            #pragma unroll
            for (int qt = 0; qt < 2; qt++) {
                const float p0 = exp2_fast(sv[qt][0]), p1 = exp2_fast(sv[qt][1]);
                const float p2 = exp2_fast(sv[qt][2]), p3 = exp2_fast(sv[qt][3]);
                lsum[qt] += (p0 + p1) + (p2 + p3);
                bfu[qt].z = __builtin_bit_cast(unsigned int, __builtin_amdgcn_cvt_pkrtz(p0, p1));
                bfu[qt].w = __builtin_bit_cast(unsigned int, __builtin_amdgcn_cvt_pkrtz(p2, p3));
            }
        }

        // ======== PV over the 32-key group: k=32 MFMA, pure-MFMA cluster ====
        const ushort* vb = myL + 2048;
        __builtin_amdgcn_s_setprio(1);
        #pragma unroll
        for (int dt = 0; dt < 4; dt++) {
            f16x8 vfr = *(const f16x8*)&vb[(dt * 16 + c) * 32 + vxo];
            acc[dt][0] = __builtin_amdgcn_mfma_f32_16x16x32_f16(
                vfr, __builtin_bit_cast(f16x8, bfu[0]), acc[dt][0], 0, 0, 0);
            acc[dt][1] = __builtin_amdgcn_mfma_f32_16x16x32_f16(
                vfr, __builtin_bit_cast(f16x8, bfu[1]), acc[dt][1], 0, 0, 0);
        }
        __builtin_amdgcn_s_setprio(0);

        // ======== issue V(T+1) into the (single) V buffer ========
        if (T < 15) {
            __builtin_amdgcn_sched_barrier(0);   // keep DMA after PV's reads
            gload_lds16(vstA, myL + 2048);
            gload_lds16(vstB, myL + 2560);
            vstA += 1024; vstB += 1024;
            gload_lds16(vstA, myL + 3072);
            gload_lds16(vstB, myL + 3584);
            vstA += 7168; vstB += 7168;
        }
        // NO barrier: next iter only touches this wave's private region
    }

    __syncthreads();   // all waves done computing; LDS becomes reduce scratch

    // ---- cross-wave reduction (once per block) ----
    float* red = (float*)&L[0];        // 4 slots x 512 floats = 8KB
    float* lsr = (float*)&L[4096];     // bytes 8K..8.5K: 4 waves x 32 queries

    #pragma unroll
    for (int qt = 0; qt < 2; qt++) {
        float v = lsum[qt];
        v += __shfl_xor(v, 16);
        v += __shfl_xor(v, 32);
        lsum[qt] = v;
    }
    if (lane < 16) {
        #pragma unroll
        for (int qt = 0; qt < 2; qt++) lsr[wv * 32 + qt * 16 + lane] = lsum[qt];
    }

    f32x4 own[2];                  // this wave owns d-tile dt == wv
    #pragma unroll
    for (int qt = 0; qt < 2; qt++)
        own[qt] = (wv == 0) ? acc[0][qt] : (wv == 1) ? acc[1][qt]
                : (wv == 2) ? acc[2][qt] : acc[3][qt];

    #pragma unroll
    for (int r = 1; r < 4; r++) {
        const int ds = (wv + r) & 3;          // distinct slots per wave
        #pragma unroll
        for (int qt = 0; qt < 2; qt++) {
            f32x4 sv = (ds == 0) ? acc[0][qt] : (ds == 1) ? acc[1][qt]
                     : (ds == 2) ? acc[2][qt] : acc[3][qt];
            *(f32x4*)&red[ds * 512 + qt * 256 + lane * 4] = sv;
        }
        __syncthreads();
        #pragma unroll
        for (int qt = 0; qt < 2; qt++)
            own[qt] += *(const f32x4*)&red[wv * 512 + qt * 256 + lane * 4];
        if (r < 3) __syncthreads();
    }

    float inv[2];
    #pragma unroll
    for (int qt = 0; qt < 2; qt++) {
        const int q = qt * 16 + c;
        inv[qt] = 1.0f / (lsr[q] + lsr[32 + q] + lsr[64 + q] + lsr[96 + q]);
    }

    // store: lane holds q = qt*16+c, d = wv*16 + qd*4 + (0..3); ctx unswizzled
    const size_t obase = qrow0 * E_ + h * 64 + wv * 16 + qd * 4;
    #pragma unroll
    for (int qt = 0; qt < 2; qt++) {
        f32x4 v = own[qt];
        const float iq = inv[qt];
        ushort4 o = make_ushort4(f2h(v[0] * iq), f2h(v[1] * iq),
                                 f2h(v[2] * iq), f2h(v[3] * iq));
        *(ushort4*)&ctxf[obase + (size_t)(qt * 16 + c) * E_] = o;
    }
}

// ---------------- launch ----------------
extern "C" void kernel_launch(void* const* d_in, const int* in_sizes, int n_in,
                              void* d_out, int out_size, void* d_ws, size_t ws_size,
                              hipStream_t stream)
{
    const float* x  = (const float*)d_in[0];
    const float* Wq = (const float*)d_in[1];
    const float* bq = (const float*)d_in[2];
    const float* Wk = (const float*)d_in[3];
    const float* bk = (const float*)d_in[4];
    const float* Wv = (const float*)d_in[5];
    const float* bv = (const float*)d_in[6];
    const float* Wo = (const float*)d_in[7];
    const float* bo = (const float*)d_in[8];
    float* out = (float*)d_out;

    // ws (ushort units): Qb|Kb|Vf|xf (4M each) | WT (4x1M) | ct|st (fp32)
    // alias: ctxf -> Qb (each attn block writes exactly the Q-tile region it
    // alone reads, after its last read — no cross-block hazard)
    ushort* Qb = (ushort*)d_ws;
    ushort* Kb = Qb + (size_t)M_ * E_;
    ushort* Vf = Kb + (size_t)M_ * E_;
    ushort* xf = Vf + (size_t)M_ * E_;
    ushort* WT = xf + (size_t)M_ * E_;
    float*  ct = (float*)(WT + (size_t)4 * E_ * E_);
    float*  st = ct + S_ * 32;
    ushort* ctxf = Qb;

    hipLaunchKernelGGL(prep_kernel, dim3(3328), dim3(256), 0, stream,
                       x, Wq, Wk, Wv, Wo, xf, WT, ct, st);

    // fused QKV: flat 256 blocks/mode (XCD-aware m-major), z = mode
    hipLaunchKernelGGL(gemm_f16, dim3(256, 1, 3), dim3(256), 0, stream,
                       xf, WT, bq, bk, bv, ct, st,
                       Qb, Kb, Vf);

    // attn: 2048 blocks (32 q-rows each) = 2 exact rounds at 4 blocks/CU
    hipLaunchKernelGGL(attn_mfma, dim3(B_ * H_ * (S_ / 32)), dim3(256), 0, stream,
                       Qb, Kb, Vf, ctxf);

    // output projection: 64x128 tiles, 512 blocks = 2/CU
    hipLaunchKernelGGL(gemm_proj, dim3(512), dim3(256), 0, stream,
                       ctxf, WT + (size_t)3 * E_ * E_, bo, out);
}

// Round 9
// 183.119 us; speedup vs baseline: 1.0961x; 1.0961x over previous
//
#include <hip/hip_runtime.h>
#include <math.h>

#define B_ 2
#define S_ 2048
#define E_ 1024
#define H_ 16
#define D_ 64
#define M_ (B_*S_)   // 4096 rows

typedef _Float16 f16x8  __attribute__((ext_vector_type(8)));
typedef _Float16 f16x4v __attribute__((ext_vector_type(4)));
typedef __fp16   h16x2  __attribute__((ext_vector_type(2)));
typedef float    f32x4  __attribute__((ext_vector_type(4)));

__device__ __forceinline__ ushort f2h(float f) {
    _Float16 h = (_Float16)f;               // RNE
    return __builtin_bit_cast(ushort, h);
}

// async global->LDS, 16B per lane; LDS dest = wave-uniform base + lane*16.
// NOTE (R5 post-mortem): the builtin's imm-offset arg applies to BOTH the
// global and LDS addresses — do not use it for "global-only" offsets.
__device__ __forceinline__ void gload_lds16(const ushort* g, ushort* l) {
    __builtin_amdgcn_global_load_lds(
        (const __attribute__((address_space(1))) unsigned int*)g,
        (__attribute__((address_space(3))) unsigned int*)l, 16, 0, 0);
}

// 2^x via v_exp_f32 (avoid __exp2f: glibc reserves that name)
__device__ __forceinline__ float exp2_fast(float x) {
    return __builtin_amdgcn_exp2f(x);
}

// ---------------- fused prep: W transpose+cast | x cast | RoPE table --------
__global__ void prep_kernel(const float* __restrict__ x,
                            const float* __restrict__ W0, const float* __restrict__ W1,
                            const float* __restrict__ W2, const float* __restrict__ W3,
                            ushort* __restrict__ xf, ushort* __restrict__ WT,
                            float* __restrict__ ct, float* __restrict__ st)
{
    const int bid = blockIdx.x;
    const int tid = threadIdx.x;
    __shared__ float tile[32][33];

    if (bid < 2048) {                       // ---- W transpose + f16 cast ----
        const int z = bid >> 9, rem = bid & 511;
        const int kp = rem >> 5, nb = (rem & 31) * 32;
        const float* W = (z == 0) ? W0 : (z == 1) ? W1 : (z == 2) ? W2 : W3;
        const size_t zoff = (size_t)z * E_ * E_;
        const int tx = tid & 31, ty = tid >> 5;   // 32 x 8
        #pragma unroll
        for (int kk = 0; kk < 2; kk++) {
            const int k0 = kp * 64 + kk * 32;
            #pragma unroll
            for (int i = 0; i < 4; i++) {
                int r = i * 8 + ty;
                tile[r][tx] = W[(size_t)(k0 + r) * E_ + nb + tx];
            }
            __syncthreads();
            #pragma unroll
            for (int i = 0; i < 4; i++) {
                int r = i * 8 + ty;                 // local n
                WT[zoff + (size_t)(nb + r) * E_ + k0 + tx] = f2h(tile[tx][r]);
            }
            __syncthreads();
        }
    } else if (bid < 3072) {                // ---- x fp32 -> f16 ----
        const int base = (bid - 2048) * 4096 + tid * 4;
        #pragma unroll
        for (int j = 0; j < 4; j++) {
            const int i = base + j * 1024;
            float4 v = *(const float4*)&x[i];
            *(ushort4*)&xf[i] = make_ushort4(f2h(v.x), f2h(v.y), f2h(v.z), f2h(v.w));
        }
    } else {                                // ---- RoPE cos/sin table ----
        const int i = (bid - 3072) * 256 + tid;   // < S_*32
        const int j = i & 31, pos = i >> 5;
        float invf = (float)pow(10000.0, -(double)j / 32.0);
        float ang  = (float)pos * invf;
        ct[i] = (float)cos((double)ang);
        st[i] = (float)sin((double)ang);
    }
}

// ---------------- f16 MFMA GEMM: 3-buffer pipeline, raw-barrier K-loop ------
// modes: 0 = Q (bias+RoPE+0.125*log2e, f16, 16B-chunk XOR-swizzled cols),
//        1 = K (same swizzle, no scale),
//        2 = V (32-key-group strips with k-slot permutation + octet swizzle)
#define GBM 128
#define GBN 128
#define GBK 32
#define LOG2E 1.44269504088896340736f

__global__ __launch_bounds__(256, 3)
void gemm_f16(const ushort* __restrict__ A, const ushort* __restrict__ WTp,
              const float* __restrict__ b0, const float* __restrict__ b1,
              const float* __restrict__ b2,
              const float* __restrict__ ct, const float* __restrict__ st,
              ushort* __restrict__ outQ, ushort* __restrict__ outK,
              ushort* __restrict__ outV)
{
    __shared__ __align__(16) ushort lA[3][GBM * GBK];   // [buf][r][k], unpadded (DMA contract)
    __shared__ __align__(16) ushort lB[3][GBN * GBK];   // W^T tile: [buf][n][k]

    const int tid  = threadIdx.x;
    const int wv   = tid >> 6, lane = tid & 63;
    const int c    = lane & 15, qd = lane >> 4;
    const int rh   = wv >> 1, chn = wv & 1;

    const int mode = (int)blockIdx.z;
    const size_t zoff = (size_t)blockIdx.z * (E_ * E_);
    const ushort* Bt = WTp + zoff;

    // XCD-aware flat mapping: same-m blocks land on the same XCD
    const int m0 = (blockIdx.x & 31) * GBM;
    const int n0 = (blockIdx.x >> 5) * GBN;

    const ushort* gsrc = (wv < 2) ? A : Bt;
    const int rowbase = ((wv < 2) ? m0 : n0) + (wv & 1) * 64;
    const int lofs = (wv & 1) * 64 * GBK;
    const int srow = lane >> 2;
    const int soct = (lane & 3) * 8;

    f32x4 acc[4][4] = {};

    // ---- prologue: stage tiles 0 and 1 into buffers 0 and 1 ----
    #pragma unroll
    for (int pt = 0; pt < 2; pt++) {
        ushort* dst = ((wv < 2) ? &lA[pt][0] : &lB[pt][0]) + lofs;
        const int k0i = pt * GBK;
        #pragma unroll
        for (int cc = 0; cc < 4; cc++) {
            const ushort* g = gsrc + (size_t)(rowbase + cc * 16 + srow) * E_ + k0i + soct;
            gload_lds16(g, dst + cc * 512);
        }
    }
    __builtin_amdgcn_s_waitcnt(0x0F74);   // vmcnt(4): tile0 landed, tile1 flying
    __builtin_amdgcn_s_barrier();

    for (int t = 0; t < E_ / GBK; t++) {
        // ---- issue tile t+2's DMA (kept in flight across the barrier) ----
        if (t + 2 < E_ / GBK) {
            const int bi = (t + 2) % 3;
            const int k0i = (t + 2) * GBK;
            ushort* dst = ((wv < 2) ? &lA[bi][0] : &lB[bi][0]) + lofs;
            #pragma unroll
            for (int cc = 0; cc < 4; cc++) {
                const ushort* g = gsrc + (size_t)(rowbase + cc * 16 + srow) * E_ + k0i + soct;
                gload_lds16(g, dst + cc * 512);
            }
        }

        const ushort* Ab = lA[t % 3];
        const ushort* Bb = lB[t % 3];

        f16x8 af[4], bf[4];
        #pragma unroll
        for (int mt = 0; mt < 4; mt++)
            af[mt] = *(const f16x8*)&Ab[(rh * 64 + mt * 16 + c) * GBK + qd * 8];
        #pragma unroll
        for (int nt = 0; nt < 4; nt++)
            bf[nt] = *(const f16x8*)&Bb[(chn * 64 + nt * 16 + c) * GBK + qd * 8];
        #pragma unroll
        for (int mt = 0; mt < 4; mt++)
            #pragma unroll
            for (int nt = 0; nt < 4; nt++)
                acc[mt][nt] = __builtin_amdgcn_mfma_f32_16x16x32_f16(af[mt], bf[nt], acc[mt][nt], 0, 0, 0);

        // ---- publish t+1 without draining t+2 ----
        if (t < E_ / GBK - 2) {
            __builtin_amdgcn_s_waitcnt(0x0F74);   // vmcnt(4): t+1 landed
            __builtin_amdgcn_s_barrier();
        } else if (t == E_ / GBK - 2) {
            __builtin_amdgcn_s_waitcnt(0x0F70);   // vmcnt(0): last tile landed
            __builtin_amdgcn_s_barrier();
        }
    }

    const float* bias = (mode == 0) ? b0 : (mode == 1) ? b1 : b2;
    const int colbase = n0 + chn * 64;                // head-aligned (64)

    if (mode == 2) {
        // V strips: Vf[bh][g(64 groups of 32 keys)][d(64)][kslot(32)], 4KB/group.
        // kslot = q*8 + h*4 + j for key k32 = h*16+q*4+j; octet swz oct^((d>>2)&3).
        const int hd = colbase >> 6;
        const int xr = (c >> 2) & 3;              // (d>>2)&3 for d = nt*16+c
        #pragma unroll
        for (int mt = 0; mt < 4; mt++)
            #pragma unroll
            for (int r = 0; r < 4; r++) {
                const int row = m0 + rh * 64 + mt * 16 + qd * 4 + r;
                const int bb = row >> 11, sl = row & (S_ - 1);
                const int g  = sl >> 5, k32 = sl & 31;
                const int q2 = (k32 >> 2) & 3, kh = k32 >> 4, kj = k32 & 3;
                const size_t base = (size_t)(bb * H_ + hd) * (S_ * D_)
                                  + g * 2048 + ((q2 ^ xr) << 3) + kh * 4 + kj;
                #pragma unroll
                for (int nt = 0; nt < 4; nt++) {
                    const int d = nt * 16 + c;        // 0..63 within head
                    outV[base + (size_t)d * 32] = f2h(acc[mt][nt][r] + bias[colbase + d]);
                }
            }
    } else {
        // Q/K: RoPE pair (j, j+32); cols stored 16B-chunk-swizzled: ch' = ch ^ (row&7)
        ushort* O = (mode == 0) ? outQ : outK;
        const float sc = (mode == 0) ? 0.125f * LOG2E : 1.0f;   // exp2 path in attn
        #pragma unroll
        for (int mt = 0; mt < 4; mt++)
            #pragma unroll
            for (int r = 0; r < 4; r++) {
                const int row = m0 + rh * 64 + mt * 16 + qd * 4 + r;
                const int pos = row & (S_ - 1);
                const int sw = row & 7;
                #pragma unroll
                for (int p = 0; p < 2; p++) {
                    const int j32 = p * 16 + c;
                    const float cth = ct[pos * 32 + j32], sth = st[pos * 32 + j32];
                    const float v1 = acc[mt][p][r]     + bias[colbase + p * 16 + c];
                    const float v2 = acc[mt][p + 2][r] + bias[colbase + (p + 2) * 16 + c];
                    const float o1 = (v1 * cth - v2 * sth) * sc;   // col cd1
                    const float o2 = (v2 * cth + v1 * sth) * sc;   // col cd1+32
                    const int cd1 = p * 16 + c, cd2 = cd1 + 32;
                    O[(size_t)row * E_ + colbase + (((cd1 >> 3) ^ sw) * 8) + (cd1 & 7)] = f2h(o1);
                    O[(size_t)row * E_ + colbase + (((cd2 >> 3) ^ sw) * 8) + (cd2 & 7)] = f2h(o2);
                }
            }
    }
}

// ---------------- out-proj GEMM: 64x128 tiles, 512 blocks = 2/CU exact ------
__global__ __launch_bounds__(256, 3)
void gemm_proj(const ushort* __restrict__ A, const ushort* __restrict__ WTp,
               const float* __restrict__ bo, float* __restrict__ outF)
{
    __shared__ __align__(16) ushort lA[3][64 * GBK];    // 4KB per buf
    __shared__ __align__(16) ushort lB[3][GBN * GBK];   // 8KB per buf

    const int tid  = threadIdx.x;
    const int wv   = tid >> 6, lane = tid & 63;
    const int c    = lane & 15, qd = lane >> 4;

    const int m0 = (blockIdx.x & 63) * 64;
    const int n0 = (blockIdx.x >> 6) * GBN;

    const bool stager = (wv < 3);
    const ushort* gsrc = (wv == 0) ? A : WTp;
    const int rowbase = (wv == 0) ? m0 : (n0 + (wv - 1) * 64);
    const int lofs = (wv == 0) ? 0 : (wv - 1) * 64 * GBK;
    const int srow = lane >> 2;
    const int soct = (lane & 3) * 8;

    f32x4 acc[4][2] = {};

    #pragma unroll
    for (int pt = 0; pt < 2; pt++) {
        if (stager) {
            ushort* dst = ((wv == 0) ? &lA[pt][0] : &lB[pt][0]) + lofs;
            const int k0i = pt * GBK;
            #pragma unroll
            for (int cc = 0; cc < 4; cc++) {
                const ushort* g = gsrc + (size_t)(rowbase + cc * 16 + srow) * E_ + k0i + soct;
                gload_lds16(g, dst + cc * 512);
            }
        }
    }
    __builtin_amdgcn_s_waitcnt(0x0F74);   // vmcnt(4) (wave3: trivial)
    __builtin_amdgcn_s_barrier();

    for (int t = 0; t < E_ / GBK; t++) {
        if (t + 2 < E_ / GBK && stager) {
            const int bi = (t + 2) % 3;
            const int k0i = (t + 2) * GBK;
            ushort* dst = ((wv == 0) ? &lA[bi][0] : &lB[bi][0]) + lofs;
            #pragma unroll
            for (int cc = 0; cc < 4; cc++) {
                const ushort* g = gsrc + (size_t)(rowbase + cc * 16 + srow) * E_ + k0i + soct;
                gload_lds16(g, dst + cc * 512);
            }
        }

        const ushort* Ab = lA[t % 3];
        const ushort* Bb = lB[t % 3];

        f16x8 af[4], bf[2];
        #pragma unroll
        for (int mt = 0; mt < 4; mt++)
            af[mt] = *(const f16x8*)&Ab[(mt * 16 + c) * GBK + qd * 8];
        #pragma unroll
        for (int nt = 0; nt < 2; nt++)
            bf[nt] = *(const f16x8*)&Bb[(wv * 32 + nt * 16 + c) * GBK + qd * 8];
        #pragma unroll
        for (int mt = 0; mt < 4; mt++)
            #pragma unroll
            for (int nt = 0; nt < 2; nt++)
                acc[mt][nt] = __builtin_amdgcn_mfma_f32_16x16x32_f16(af[mt], bf[nt], acc[mt][nt], 0, 0, 0);

        if (t < E_ / GBK - 2) {
            __builtin_amdgcn_s_waitcnt(0x0F74);
            __builtin_amdgcn_s_barrier();
        } else if (t == E_ / GBK - 2) {
            __builtin_amdgcn_s_waitcnt(0x0F70);
            __builtin_amdgcn_s_barrier();
        }
    }

    #pragma unroll
    for (int mt = 0; mt < 4; mt++)
        #pragma unroll
        for (int r = 0; r < 4; r++) {
            const int row = m0 + mt * 16 + qd * 4 + r;
            #pragma unroll
            for (int nt = 0; nt < 2; nt++) {
                const int col = n0 + wv * 32 + nt * 16 + c;
                outF[(size_t)row * E_ + col] = acc[mt][nt][r] + bo[col];
            }
        }
}

// ---------------- MFMA flash attention: full-iter prefetch, 64q blocks ------
// R9: R7 shape (64 q-rows, 1024 blocks, 3/CU — R8 showed shrinking the q-tile
// doubles staging per q-row and LOSES) with the pipeline restructured for
// full-iteration prefetch distance: each phase does
//   wait -> ds_read frags to regs -> lgkmcnt(0)+sched_barrier (buffer free)
//   -> issue the SAME buffer's next-tile DMA -> MFMA/VALU.
// R7 waited on DMAs issued only ~0.5 iter earlier (~250cy, marginal vs L2
// ~200-225cy + queueing); now every DMA has ~1 full iter (~600cy) in flight.
// V becomes single-buffered (read-then-overwrite) -> LDS 8KB/wave = 32KB/blk.
// Steady-state ladder (8 DMAs in flight): sub0 vmcnt(6), sub1 vmcnt(6),
// PV vmcnt(4); last iter 6/4/0.
__global__ __launch_bounds__(256, 3)
void attn_mfma(const ushort* __restrict__ Qf, const ushort* __restrict__ Kf,
               const ushort* __restrict__ Vfg, ushort* __restrict__ ctxf)
{
    __shared__ __align__(16) ushort L[16384];   // 32KB: 4 waves x (K 2x2KB | V 4KB)

    const int tid = threadIdx.x;
    const int wv = tid >> 6, lane = tid & 63;
    const int c = lane & 15, qd = lane >> 4;
    const int cs = c & 7;

    // XCD swizzle: 4 bh per XCD (2MB K/V < 4MB L2/XCD)
    const int xcd = blockIdx.x & 7, ii = blockIdx.x >> 3;
    const int bh = xcd * 4 + (ii & 3);
    const int qtb = ii >> 2;
    const int b = bh >> 4, h = bh & 15;
    const int q0 = qtb * 64;

    const size_t qrow0 = (size_t)b * S_ + q0;
    const size_t krow0 = (size_t)b * S_;
    const size_t vbase = (size_t)bh * (S_ * D_);

    const int l8 = lane >> 3, l7 = lane & 7;

    // ---- stage Q tile (8KB) cooperatively, pull B-fragments ----
    #pragma unroll
    for (int j = 0; j < 2; j++) {
        const int row = wv * 16 + j * 8 + l8;
        gload_lds16(Qf + (qrow0 + row) * E_ + h * 64 + l7 * 8, &L[wv * 1024 + j * 512]);
    }
    __syncthreads();
    f16x8 qfrag[4][2];
    #pragma unroll
    for (int qt = 0; qt < 4; qt++)
        #pragma unroll
        for (int kc = 0; kc < 2; kc++)
            qfrag[qt][kc] = *(const f16x8*)&L[(qt * 16 + c) * 64 + (((kc * 4 + qd) ^ cs) * 8)];
    __syncthreads();

    f32x4 acc[4][4] = {};          // [dt][qt]: O^T partial over this wave's keys
    float lsum[4] = {0.f, 0.f, 0.f, 0.f};

    ushort* const myL = &L[wv * 4096];      // K buf0 [0,1024), buf1 [1024,2048); V [2048,4096)
    const int vxo = (qd ^ ((c >> 2) & 3)) << 3;   // V octet swizzle (matches mode-2 store)

    // staging pointers (point at the NEXT half-tile to issue)
    const ushort* kst0 = Kf + (krow0 + wv * 32 + l8) * E_ + h * 64 + l7 * 8;
    const ushort* kst1 = kst0 + 8 * E_;
    const ushort* vstA = Vfg + vbase + (size_t)wv * 2048 + lane * 8;
    const ushort* vstB = vstA + 512;

    // ---- prologue: Kh0(0), Kh1(0), V(0) -> 8 DMAs in flight ----
    gload_lds16(kst0, myL);
    gload_lds16(kst1, myL + 512);
    kst0 += 16 * E_; kst1 += 16 * E_;
    gload_lds16(kst0, myL + 1024);
    gload_lds16(kst1, myL + 1536);
    kst0 += 112 * E_; kst1 += 112 * E_;
    gload_lds16(vstA, myL + 2048);
    gload_lds16(vstB, myL + 2560);
    vstA += 1024; vstB += 1024;
    gload_lds16(vstA, myL + 3072);
    gload_lds16(vstB, myL + 3584);
    vstA += 7168; vstB += 7168;

    #pragma unroll 1
    for (int T = 0; T < 16; T++) {
        uint4 bfu[4];                       // packed P (f16x8) per q-tile

        // ======== sub-iter 0: QK over keys 0..15 of group T*4+wv ========
        {
            __builtin_amdgcn_s_waitcnt(0x0F76);   // vmcnt(6): Kh0(T) landed
            const ushort* kb = myL;               // K buf 0
            f16x8 kf0 = *(const f16x8*)&kb[c * 64 + ((qd ^ cs) * 8)];
            f16x8 kf1 = *(const f16x8*)&kb[c * 64 + (((4 + qd) ^ cs) * 8)];
            __builtin_amdgcn_s_waitcnt(0xC07F);   // lgkmcnt(0): kf in regs, buf0 free
            __builtin_amdgcn_sched_barrier(0);
            if (T < 15) {                         // issue Kh0(T+1) into buf0 (full iter in flight)
                gload_lds16(kst0, myL);
                gload_lds16(kst1, myL + 512);
                kst0 += 16 * E_; kst1 += 16 * E_;
            }
            f32x4 sv[4];
            __builtin_amdgcn_s_setprio(1);
            #pragma unroll
            for (int qt = 0; qt < 4; qt++) {
                f32x4 s = {};
                s = __builtin_amdgcn_mfma_f32_16x16x32_f16(kf0, qfrag[qt][0], s, 0, 0, 0);
                sv[qt] = __builtin_amdgcn_mfma_f32_16x16x32_f16(kf1, qfrag[qt][1], s, 0, 0, 0);
            }
            __builtin_amdgcn_s_setprio(0);
            #pragma unroll
            for (int qt = 0; qt < 4; qt++) {
                const float p0 = exp2_fast(sv[qt][0]), p1 = exp2_fast(sv[qt][1]);
                const float p2 = exp2_fast(sv[qt][2]), p3 = exp2_fast(sv[qt][3]);
                lsum[qt] += (p0 + p1) + (p2 + p3);
                bfu[qt].x = __builtin_bit_cast(unsigned int, __builtin_amdgcn_cvt_pkrtz(p0, p1));
                bfu[qt].y = __builtin_bit_cast(unsigned int, __builtin_amdgcn_cvt_pkrtz(p2, p3));
            }
        }

        // ======== sub-iter 1: QK over keys 16..31 ========
        {
            if (T < 15) __builtin_amdgcn_s_waitcnt(0x0F76);   // vmcnt(6): Kh1(T) landed
            else        __builtin_amdgcn_s_waitcnt(0x0F74);   // vmcnt(4): last iter
            const ushort* kb = myL + 1024;        // K buf 1
            f16x8 kf0 = *(const f16x8*)&kb[c * 64 + ((qd ^ cs) * 8)];
            f16x8 kf1 = *(const f16x8*)&kb[c * 64 + (((4 + qd) ^ cs) * 8)];
            __builtin_amdgcn_s_waitcnt(0xC07F);   // lgkmcnt(0): buf1 free
            __builtin_amdgcn_sched_barrier(0);
            if (T < 15) {                         // issue Kh1(T+1) into buf1
                gload_lds16(kst0, myL + 1024);
                gload_lds16(kst1, myL + 1536);
                kst0 += 112 * E_; kst1 += 112 * E_;
            }
            f32x4 sv[4];
            __builtin_amdgcn_s_setprio(1);
            #pragma unroll
            for (int qt = 0; qt < 4; qt++) {
                f32x4 s = {};
                s = __builtin_amdgcn_mfma_f32_16x16x32_f16(kf0, qfrag[qt][0], s, 0, 0, 0);
                sv[qt] = __builtin_amdgcn_mfma_f32_16x16x32_f16(kf1, qfrag[qt][1], s, 0, 0, 0);
            }
            __builtin_amdgcn_s_setprio(0);
            #pragma unroll
            for (int qt = 0; qt < 4; qt++) {
                const float p0 = exp2_fast(sv[qt][0]), p1 = exp2_fast(sv[qt][1]);
                const float p2 = exp2_fast(sv[qt][2]), p3 = exp2_fast(sv[qt][3]);
                lsum[qt] += (p0 + p1) + (p2 + p3);
                bfu[qt].z = __builtin_bit_cast(unsigned int, __builtin_amdgcn_cvt_pkrtz(p0, p1));
                bfu[qt].w = __builtin_bit_cast(unsigned int, __builtin_amdgcn_cvt_pkrtz(p2, p3));
            }
        }

        // ======== PV: read V(T) to regs, issue V(T+1), k=32 MFMA cluster ====
        {
            if (T < 15) __builtin_amdgcn_s_waitcnt(0x0F74);   // vmcnt(4): V(T) landed
            else        __builtin_amdgcn_s_waitcnt(0x0F70);   // vmcnt(0): all done
            const ushort* vb = myL + 2048;
            f16x8 vf0 = *(const f16x8*)&vb[(0 * 16 + c) * 32 + vxo];
            f16x8 vf1 = *(const f16x8*)&vb[(1 * 16 + c) * 32 + vxo];
            f16x8 vf2 = *(const f16x8*)&vb[(2 * 16 + c) * 32 + vxo];
            f16x8 vf3 = *(const f16x8*)&vb[(3 * 16 + c) * 32 + vxo];
            __builtin_amdgcn_s_waitcnt(0xC07F);   // lgkmcnt(0): V frags in regs, buffer free
            __builtin_amdgcn_sched_barrier(0);
            if (T < 15) {                         // issue V(T+1) into the single V buffer
                gload_lds16(vstA, myL + 2048);
                gload_lds16(vstB, myL + 2560);
                vstA += 1024; vstB += 1024;
                gload_lds16(vstA, myL + 3072);
                gload_lds16(vstB, myL + 3584);
                vstA += 7168; vstB += 7168;
            }
            __builtin_amdgcn_s_setprio(1);
            #pragma unroll
            for (int qt = 0; qt < 4; qt++) {
                const f16x8 pb = __builtin_bit_cast(f16x8, bfu[qt]);
                acc[0][qt] = __builtin_amdgcn_mfma_f32_16x16x32_f16(vf0, pb, acc[0][qt], 0, 0, 0);
                acc[1][qt] = __builtin_amdgcn_mfma_f32_16x16x32_f16(vf1, pb, acc[1][qt], 0, 0, 0);
                acc[2][qt] = __builtin_amdgcn_mfma_f32_16x16x32_f16(vf2, pb, acc[2][qt], 0, 0, 0);
                acc[3][qt] = __builtin_amdgcn_mfma_f32_16x16x32_f16(vf3, pb, acc[3][qt], 0, 0, 0);
            }
            __builtin_amdgcn_s_setprio(0);
        }
        // NO barrier: next iter only touches this wave's private region
    }

    __syncthreads();   // all waves done computing; LDS becomes reduce scratch

    // ---- cross-wave reduction (once per block) ----
    float* red = (float*)&L[0];        // 4 slots x 1024 floats = 16KB
    float* lsr = (float*)&L[8192];     // bytes 16K..17K: 4 waves x 64 queries

    #pragma unroll
    for (int qt = 0; qt < 4; qt++) {
        float v = lsum[qt];
        v += __shfl_xor(v, 16);
        v += __shfl_xor(v, 32);
        lsum[qt] = v;
    }
    if (lane < 16) {
        #pragma unroll
        for (int qt = 0; qt < 4; qt++) lsr[wv * 64 + qt * 16 + lane] = lsum[qt];
    }

    f32x4 own[4];                  // this wave owns d-tile dt == wv
    #pragma unroll
    for (int qt = 0; qt < 4; qt++)
        own[qt] = (wv == 0) ? acc[0][qt] : (wv == 1) ? acc[1][qt]
                : (wv == 2) ? acc[2][qt] : acc[3][qt];

    #pragma unroll
    for (int r = 1; r < 4; r++) {
        const int ds = (wv + r) & 3;          // distinct slots per wave
        #pragma unroll
        for (int qt = 0; qt < 4; qt++) {
            f32x4 sv = (ds == 0) ? acc[0][qt] : (ds == 1) ? acc[1][qt]
                     : (ds == 2) ? acc[2][qt] : acc[3][qt];
            *(f32x4*)&red[ds * 1024 + qt * 256 + lane * 4] = sv;
        }
        __syncthreads();
        #pragma unroll
        for (int qt = 0; qt < 4; qt++)
            own[qt] += *(const f32x4*)&red[wv * 1024 + qt * 256 + lane * 4];
        if (r < 3) __syncthreads();
    }

    float inv[4];
    #pragma unroll
    for (int qt = 0; qt < 4; qt++) {
        const int q = qt * 16 + c;
        inv[qt] = 1.0f / (lsr[q] + lsr[64 + q] + lsr[128 + q] + lsr[192 + q]);
    }

    // store: lane holds q = qt*16+c, d = wv*16 + qd*4 + (0..3); ctx unswizzled
    const size_t obase = qrow0 * E_ + h * 64 + wv * 16 + qd * 4;
    #pragma unroll
    for (int qt = 0; qt < 4; qt++) {
        f32x4 v = own[qt];
        const float iq = inv[qt];
        ushort4 o = make_ushort4(f2h(v[0] * iq), f2h(v[1] * iq),
                                 f2h(v[2] * iq), f2h(v[3] * iq));
        *(ushort4*)&ctxf[obase + (size_t)(qt * 16 + c) * E_] = o;
    }
}

// ---------------- launch ----------------
extern "C" void kernel_launch(void* const* d_in, const int* in_sizes, int n_in,
                              void* d_out, int out_size, void* d_ws, size_t ws_size,
                              hipStream_t stream)
{
    const float* x  = (const float*)d_in[0];
    const float* Wq = (const float*)d_in[1];
    const float* bq = (const float*)d_in[2];
    const float* Wk = (const float*)d_in[3];
    const float* bk = (const float*)d_in[4];
    const float* Wv = (const float*)d_in[5];
    const float* bv = (const float*)d_in[6];
    const float* Wo = (const float*)d_in[7];
    const float* bo = (const float*)d_in[8];
    float* out = (float*)d_out;

    // ws (ushort units): Qb|Kb|Vf|xf (4M each) | WT (4x1M) | ct|st (fp32)
    // alias: ctxf -> Qb (each attn block writes exactly the Q-tile region it
    // alone reads, after its last read — no cross-block hazard)
    ushort* Qb = (ushort*)d_ws;
    ushort* Kb = Qb + (size_t)M_ * E_;
    ushort* Vf = Kb + (size_t)M_ * E_;
    ushort* xf = Vf + (size_t)M_ * E_;
    ushort* WT = xf + (size_t)M_ * E_;
    float*  ct = (float*)(WT + (size_t)4 * E_ * E_);
    float*  st = ct + S_ * 32;
    ushort* ctxf = Qb;

    hipLaunchKernelGGL(prep_kernel, dim3(3328), dim3(256), 0, stream,
                       x, Wq, Wk, Wv, Wo, xf, WT, ct, st);

    // fused QKV: flat 256 blocks/mode (XCD-aware m-major), z = mode
    hipLaunchKernelGGL(gemm_f16, dim3(256, 1, 3), dim3(256), 0, stream,
                       xf, WT, bq, bk, bv, ct, st,
                       Qb, Kb, Vf);

    // attn: 1024 blocks (64 q-rows each), 3 blocks/CU
    hipLaunchKernelGGL(attn_mfma, dim3(B_ * H_ * (S_ / 64)), dim3(256), 0, stream,
                       Qb, Kb, Vf, ctxf);

    // output projection: 64x128 tiles, 512 blocks = 2/CU
    hipLaunchKernelGGL(gemm_proj, dim3(512), dim3(256), 0, stream,
                       ctxf, WT + (size_t)3 * E_ * E_, bo, out);
}

// Round 10
// 180.299 us; speedup vs baseline: 1.1132x; 1.0156x over previous
//
#include <hip/hip_runtime.h>
#include <math.h>

#define B_ 2
#define S_ 2048
#define E_ 1024
#define H_ 16
#define D_ 64
#define M_ (B_*S_)   // 4096 rows

typedef _Float16 f16x8  __attribute__((ext_vector_type(8)));
typedef _Float16 f16x4v __attribute__((ext_vector_type(4)));
typedef __fp16   h16x2  __attribute__((ext_vector_type(2)));
typedef float    f32x4  __attribute__((ext_vector_type(4)));

__device__ __forceinline__ ushort f2h(float f) {
    _Float16 h = (_Float16)f;               // RNE
    return __builtin_bit_cast(ushort, h);
}

// async global->LDS, 16B per lane; LDS dest = wave-uniform base + lane*16.
// NOTE (R5 post-mortem): the builtin's imm-offset arg applies to BOTH the
// global and LDS addresses — do not use it for "global-only" offsets.
__device__ __forceinline__ void gload_lds16(const ushort* g, ushort* l) {
    __builtin_amdgcn_global_load_lds(
        (const __attribute__((address_space(1))) unsigned int*)g,
        (__attribute__((address_space(3))) unsigned int*)l, 16, 0, 0);
}

// 2^x via v_exp_f32 (avoid __exp2f: glibc reserves that name)
__device__ __forceinline__ float exp2_fast(float x) {
    return __builtin_amdgcn_exp2f(x);
}

// ---------------- fused prep: W transpose+cast | x cast | RoPE table --------
// Fat blocks (3328) — 8448 tiny blocks were dispatch-granularity-bound.
__global__ void prep_kernel(const float* __restrict__ x,
                            const float* __restrict__ W0, const float* __restrict__ W1,
                            const float* __restrict__ W2, const float* __restrict__ W3,
                            ushort* __restrict__ xf, ushort* __restrict__ WT,
                            float* __restrict__ ct, float* __restrict__ st)
{
    const int bid = blockIdx.x;
    const int tid = threadIdx.x;
    __shared__ float tile[32][33];

    if (bid < 2048) {                       // ---- W transpose + f16 cast ----
        const int z = bid >> 9, rem = bid & 511;
        const int kp = rem >> 5, nb = (rem & 31) * 32;
        const float* W = (z == 0) ? W0 : (z == 1) ? W1 : (z == 2) ? W2 : W3;
        const size_t zoff = (size_t)z * E_ * E_;
        const int tx = tid & 31, ty = tid >> 5;   // 32 x 8
        #pragma unroll
        for (int kk = 0; kk < 2; kk++) {
            const int k0 = kp * 64 + kk * 32;
            #pragma unroll
            for (int i = 0; i < 4; i++) {
                int r = i * 8 + ty;
                tile[r][tx] = W[(size_t)(k0 + r) * E_ + nb + tx];
            }
            __syncthreads();
            #pragma unroll
            for (int i = 0; i < 4; i++) {
                int r = i * 8 + ty;                 // local n
                WT[zoff + (size_t)(nb + r) * E_ + k0 + tx] = f2h(tile[tx][r]);
            }
            __syncthreads();
        }
    } else if (bid < 3072) {                // ---- x fp32 -> f16 ----
        const int base = (bid - 2048) * 4096 + tid * 4;
        #pragma unroll
        for (int j = 0; j < 4; j++) {
            const int i = base + j * 1024;
            float4 v = *(const float4*)&x[i];
            *(ushort4*)&xf[i] = make_ushort4(f2h(v.x), f2h(v.y), f2h(v.z), f2h(v.w));
        }
    } else {                                // ---- RoPE cos/sin table ----
        const int i = (bid - 3072) * 256 + tid;   // < S_*32
        const int j = i & 31, pos = i >> 5;
        float invf = (float)pow(10000.0, -(double)j / 32.0);
        float ang  = (float)pos * invf;
        ct[i] = (float)cos((double)ang);
        st[i] = (float)sin((double)ang);
    }
}

// ---------------- f16 MFMA GEMM: 3-buffer pipeline, raw-barrier K-loop ------
// modes: 0 = Q (bias+RoPE+0.125*log2e, f16, 16B-chunk XOR-swizzled cols),
//        1 = K (same swizzle, no scale),
//        2 = V (32-key-group strips with k-slot permutation + octet swizzle)
#define GBM 128
#define GBN 128
#define GBK 32
#define LOG2E 1.44269504088896340736f

__global__ __launch_bounds__(256, 3)
void gemm_f16(const ushort* __restrict__ A, const ushort* __restrict__ WTp,
              const float* __restrict__ b0, const float* __restrict__ b1,
              const float* __restrict__ b2,
              const float* __restrict__ ct, const float* __restrict__ st,
              ushort* __restrict__ outQ, ushort* __restrict__ outK,
              ushort* __restrict__ outV)
{
    __shared__ __align__(16) ushort lA[3][GBM * GBK];   // [buf][r][k], unpadded (DMA contract)
    __shared__ __align__(16) ushort lB[3][GBN * GBK];   // W^T tile: [buf][n][k]

    const int tid  = threadIdx.x;
    const int wv   = tid >> 6, lane = tid & 63;
    const int c    = lane & 15, qd = lane >> 4;
    const int rh   = wv >> 1, chn = wv & 1;

    const int mode = (int)blockIdx.z;
    const size_t zoff = (size_t)blockIdx.z * (E_ * E_);
    const ushort* Bt = WTp + zoff;

    // XCD-aware flat mapping: same-m blocks land on the same XCD
    const int m0 = (blockIdx.x & 31) * GBM;
    const int n0 = (blockIdx.x >> 5) * GBN;

    const ushort* gsrc = (wv < 2) ? A : Bt;
    const int rowbase = ((wv < 2) ? m0 : n0) + (wv & 1) * 64;
    const int lofs = (wv & 1) * 64 * GBK;
    const int srow = lane >> 2;
    const int soct = (lane & 3) * 8;

    f32x4 acc[4][4] = {};

    // ---- prologue: stage tiles 0 and 1 into buffers 0 and 1 ----
    #pragma unroll
    for (int pt = 0; pt < 2; pt++) {
        ushort* dst = ((wv < 2) ? &lA[pt][0] : &lB[pt][0]) + lofs;
        const int k0i = pt * GBK;
        #pragma unroll
        for (int cc = 0; cc < 4; cc++) {
            const ushort* g = gsrc + (size_t)(rowbase + cc * 16 + srow) * E_ + k0i + soct;
            gload_lds16(g, dst + cc * 512);
        }
    }
    __builtin_amdgcn_s_waitcnt(0x0F74);   // vmcnt(4): tile0 landed, tile1 flying
    __builtin_amdgcn_s_barrier();

    for (int t = 0; t < E_ / GBK; t++) {
        // ---- issue tile t+2's DMA (kept in flight across the barrier) ----
        if (t + 2 < E_ / GBK) {
            const int bi = (t + 2) % 3;
            const int k0i = (t + 2) * GBK;
            ushort* dst = ((wv < 2) ? &lA[bi][0] : &lB[bi][0]) + lofs;
            #pragma unroll
            for (int cc = 0; cc < 4; cc++) {
                const ushort* g = gsrc + (size_t)(rowbase + cc * 16 + srow) * E_ + k0i + soct;
                gload_lds16(g, dst + cc * 512);
            }
        }

        const ushort* Ab = lA[t % 3];
        const ushort* Bb = lB[t % 3];

        f16x8 af[4], bf[4];
        #pragma unroll
        for (int mt = 0; mt < 4; mt++)
            af[mt] = *(const f16x8*)&Ab[(rh * 64 + mt * 16 + c) * GBK + qd * 8];
        #pragma unroll
        for (int nt = 0; nt < 4; nt++)
            bf[nt] = *(const f16x8*)&Bb[(chn * 64 + nt * 16 + c) * GBK + qd * 8];
        #pragma unroll
        for (int mt = 0; mt < 4; mt++)
            #pragma unroll
            for (int nt = 0; nt < 4; nt++)
                acc[mt][nt] = __builtin_amdgcn_mfma_f32_16x16x32_f16(af[mt], bf[nt], acc[mt][nt], 0, 0, 0);

        // ---- publish t+1 without draining t+2 ----
        if (t < E_ / GBK - 2) {
            __builtin_amdgcn_s_waitcnt(0x0F74);   // vmcnt(4): t+1 landed
            __builtin_amdgcn_s_barrier();
        } else if (t == E_ / GBK - 2) {
            __builtin_amdgcn_s_waitcnt(0x0F70);   // vmcnt(0): last tile landed
            __builtin_amdgcn_s_barrier();
        }
    }

    const float* bias = (mode == 0) ? b0 : (mode == 1) ? b1 : b2;
    const int colbase = n0 + chn * 64;                // head-aligned (64)

    if (mode == 2) {
        // V strips: Vf[bh][g(64 groups of 32 keys)][d(64)][kslot(32)], 4KB/group.
        // kslot = q*8 + h*4 + j for key k32 = h*16+q*4+j; octet swz oct^((d>>2)&3).
        const int hd = colbase >> 6;
        const int xr = (c >> 2) & 3;              // (d>>2)&3 for d = nt*16+c
        #pragma unroll
        for (int mt = 0; mt < 4; mt++)
            #pragma unroll
            for (int r = 0; r < 4; r++) {
                const int row = m0 + rh * 64 + mt * 16 + qd * 4 + r;
                const int bb = row >> 11, sl = row & (S_ - 1);
                const int g  = sl >> 5, k32 = sl & 31;
                const int q2 = (k32 >> 2) & 3, kh = k32 >> 4, kj = k32 & 3;
                const size_t base = (size_t)(bb * H_ + hd) * (S_ * D_)
                                  + g * 2048 + ((q2 ^ xr) << 3) + kh * 4 + kj;
                #pragma unroll
                for (int nt = 0; nt < 4; nt++) {
                    const int d = nt * 16 + c;        // 0..63 within head
                    outV[base + (size_t)d * 32] = f2h(acc[mt][nt][r] + bias[colbase + d]);
                }
            }
    } else {
        // Q/K: RoPE pair (j, j+32); cols stored 16B-chunk-swizzled: ch' = ch ^ (row&7)
        ushort* O = (mode == 0) ? outQ : outK;
        const float sc = (mode == 0) ? 0.125f * LOG2E : 1.0f;   // exp2 path in attn
        #pragma unroll
        for (int mt = 0; mt < 4; mt++)
            #pragma unroll
            for (int r = 0; r < 4; r++) {
                const int row = m0 + rh * 64 + mt * 16 + qd * 4 + r;
                const int pos = row & (S_ - 1);
                const int sw = row & 7;
                #pragma unroll
                for (int p = 0; p < 2; p++) {
                    const int j32 = p * 16 + c;
                    const float cth = ct[pos * 32 + j32], sth = st[pos * 32 + j32];
                    const float v1 = acc[mt][p][r]     + bias[colbase + p * 16 + c];
                    const float v2 = acc[mt][p + 2][r] + bias[colbase + (p + 2) * 16 + c];
                    const float o1 = (v1 * cth - v2 * sth) * sc;   // col cd1
                    const float o2 = (v2 * cth + v1 * sth) * sc;   // col cd1+32
                    const int cd1 = p * 16 + c, cd2 = cd1 + 32;
                    O[(size_t)row * E_ + colbase + (((cd1 >> 3) ^ sw) * 8) + (cd1 & 7)] = f2h(o1);
                    O[(size_t)row * E_ + colbase + (((cd2 >> 3) ^ sw) * 8) + (cd2 & 7)] = f2h(o2);
                }
            }
    }
}

// ---------------- out-proj GEMM: 64x128 tiles, 512 blocks = 2/CU exact ------
__global__ __launch_bounds__(256, 3)
void gemm_proj(const ushort* __restrict__ A, const ushort* __restrict__ WTp,
               const float* __restrict__ bo, float* __restrict__ outF)
{
    __shared__ __align__(16) ushort lA[3][64 * GBK];    // 4KB per buf
    __shared__ __align__(16) ushort lB[3][GBN * GBK];   // 8KB per buf

    const int tid  = threadIdx.x;
    const int wv   = tid >> 6, lane = tid & 63;
    const int c    = lane & 15, qd = lane >> 4;

    const int m0 = (blockIdx.x & 63) * 64;
    const int n0 = (blockIdx.x >> 6) * GBN;

    const bool stager = (wv < 3);
    const ushort* gsrc = (wv == 0) ? A : WTp;
    const int rowbase = (wv == 0) ? m0 : (n0 + (wv - 1) * 64);
    const int lofs = (wv == 0) ? 0 : (wv - 1) * 64 * GBK;
    const int srow = lane >> 2;
    const int soct = (lane & 3) * 8;

    f32x4 acc[4][2] = {};

    #pragma unroll
    for (int pt = 0; pt < 2; pt++) {
        if (stager) {
            ushort* dst = ((wv == 0) ? &lA[pt][0] : &lB[pt][0]) + lofs;
            const int k0i = pt * GBK;
            #pragma unroll
            for (int cc = 0; cc < 4; cc++) {
                const ushort* g = gsrc + (size_t)(rowbase + cc * 16 + srow) * E_ + k0i + soct;
                gload_lds16(g, dst + cc * 512);
            }
        }
    }
    __builtin_amdgcn_s_waitcnt(0x0F74);   // vmcnt(4) (wave3: trivial)
    __builtin_amdgcn_s_barrier();

    for (int t = 0; t < E_ / GBK; t++) {
        if (t + 2 < E_ / GBK && stager) {
            const int bi = (t + 2) % 3;
            const int k0i = (t + 2) * GBK;
            ushort* dst = ((wv == 0) ? &lA[bi][0] : &lB[bi][0]) + lofs;
            #pragma unroll
            for (int cc = 0; cc < 4; cc++) {
                const ushort* g = gsrc + (size_t)(rowbase + cc * 16 + srow) * E_ + k0i + soct;
                gload_lds16(g, dst + cc * 512);
            }
        }

        const ushort* Ab = lA[t % 3];
        const ushort* Bb = lB[t % 3];

        f16x8 af[4], bf[2];
        #pragma unroll
        for (int mt = 0; mt < 4; mt++)
            af[mt] = *(const f16x8*)&Ab[(mt * 16 + c) * GBK + qd * 8];
        #pragma unroll
        for (int nt = 0; nt < 2; nt++)
            bf[nt] = *(const f16x8*)&Bb[(wv * 32 + nt * 16 + c) * GBK + qd * 8];
        #pragma unroll
        for (int mt = 0; mt < 4; mt++)
            #pragma unroll
            for (int nt = 0; nt < 2; nt++)
                acc[mt][nt] = __builtin_amdgcn_mfma_f32_16x16x32_f16(af[mt], bf[nt], acc[mt][nt], 0, 0, 0);

        if (t < E_ / GBK - 2) {
            __builtin_amdgcn_s_waitcnt(0x0F74);
            __builtin_amdgcn_s_barrier();
        } else if (t == E_ / GBK - 2) {
            __builtin_amdgcn_s_waitcnt(0x0F70);
            __builtin_amdgcn_s_barrier();
        }
    }

    #pragma unroll
    for (int mt = 0; mt < 4; mt++)
        #pragma unroll
        for (int r = 0; r < 4; r++) {
            const int row = m0 + mt * 16 + qd * 4 + r;
            #pragma unroll
            for (int nt = 0; nt < 2; nt++) {
                const int col = n0 + wv * 32 + nt * 16 + c;
                outF[(size_t)row * E_ + col] = acc[mt][nt][r] + bo[col];
            }
        }
}

// ---------------- MFMA flash attention: k=32 PV, barrier-free k-loop --------
// R7-proven version (45.9us). Each wave owns contiguous 32-key groups
// g = T*4+wv: two 16-key QK sub-iters fill one f16x8 P-fragment per q-tile
// (k-slot permutation baked into the V layout -> no cross-lane), then ONE
// k=32 PV MFMA per (dt,qt). Staging addresses strength-reduced to lockstep
// pointers; QK/PV MFMAs clustered in setprio(1).
// Post-mortem constraints (R8/R9): q-tile height amortizes per-key staging —
// do NOT shrink it for occupancy; prefetch distance is capped by the 3-block
// register budget (~170 unified) — holding frags across issue points spills.
__global__ __launch_bounds__(256, 3)
void attn_mfma(const ushort* __restrict__ Qf, const ushort* __restrict__ Kf,
               const ushort* __restrict__ Vfg, ushort* __restrict__ ctxf)
{
    __shared__ __align__(16) ushort L[24576];   // 48KB: 4 waves x (K 2x2KB | V 2x4KB)

    const int tid = threadIdx.x;
    const int wv = tid >> 6, lane = tid & 63;
    const int c = lane & 15, qd = lane >> 4;
    const int cs = c & 7;

    // XCD swizzle: 4 bh per XCD (2MB K/V < 4MB L2/XCD)
    const int xcd = blockIdx.x & 7, ii = blockIdx.x >> 3;
    const int bh = xcd * 4 + (ii & 3);
    const int qtb = ii >> 2;
    const int b = bh >> 4, h = bh & 15;
    const int q0 = qtb * 64;

    const size_t qrow0 = (size_t)b * S_ + q0;
    const size_t krow0 = (size_t)b * S_;
    const size_t vbase = (size_t)bh * (S_ * D_);

    const int l8 = lane >> 3, l7 = lane & 7;

    // ---- stage Q tile (8KB) cooperatively, pull B-fragments ----
    #pragma unroll
    for (int j = 0; j < 2; j++) {
        const int row = wv * 16 + j * 8 + l8;
        gload_lds16(Qf + (qrow0 + row) * E_ + h * 64 + l7 * 8, &L[wv * 1024 + j * 512]);
    }
    __syncthreads();
    f16x8 qfrag[4][2];
    #pragma unroll
    for (int qt = 0; qt < 4; qt++)
        #pragma unroll
        for (int kc = 0; kc < 2; kc++)
            qfrag[qt][kc] = *(const f16x8*)&L[(qt * 16 + c) * 64 + (((kc * 4 + qd) ^ cs) * 8)];
    __syncthreads();

    f32x4 acc[4][4] = {};          // [dt][qt]: O^T partial over this wave's keys
    float lsum[4] = {0.f, 0.f, 0.f, 0.f};

    ushort* const myL = &L[wv * 6144];      // K: [0|1024], V: [2048|4096] (ushorts)
    const int vxo = (qd ^ ((c >> 2) & 3)) << 3;   // V octet swizzle (matches mode-2 store)

    // ---- staging source pointers (point at the NEXT half-tile to stage) ----
    const ushort* kst0 = Kf + (krow0 + wv * 32 + l8) * E_ + h * 64 + l7 * 8;
    const ushort* kst1 = kst0 + 8 * E_;
    const ushort* vstA = Vfg + vbase + (size_t)wv * 2048 + lane * 8;
    const ushort* vstB = vstA + 512;

    // ---- prologue: stage T=0 half0 (K rows 0..15, V d-rows 0..31) ----
    gload_lds16(kst0, myL);
    gload_lds16(kst1, myL + 512);
    gload_lds16(vstA, myL + 2048);
    gload_lds16(vstB, myL + 2560);
    kst0 += 16 * E_; kst1 += 16 * E_; vstA += 1024; vstB += 1024;

    #pragma unroll 1
    for (int T = 0; T < 16; T++) {
        uint4 bfu[4];                       // packed P (f16x8) per q-tile

        // ======== sub-iter 0: stage T's half1, QK over keys 0..15 ========
        {
            ushort* vd = myL + 2048 + (T & 1) * 2048 + 1024;
            gload_lds16(kst0, myL + 1024);
            gload_lds16(kst1, myL + 1536);
            gload_lds16(vstA, vd);
            gload_lds16(vstB, vd + 512);
            kst0 += 112 * E_; kst1 += 112 * E_; vstA += 7168; vstB += 7168;
            __builtin_amdgcn_s_waitcnt(0x0F74);   // vmcnt(4): half0 landed

            const ushort* kb = myL;               // K buf 0
            f16x8 kf0 = *(const f16x8*)&kb[c * 64 + ((qd ^ cs) * 8)];
            f16x8 kf1 = *(const f16x8*)&kb[c * 64 + (((4 + qd) ^ cs) * 8)];
            f32x4 sv[4];
            __builtin_amdgcn_s_setprio(1);
            #pragma unroll
            for (int qt = 0; qt < 4; qt++) {
                f32x4 s = {};
                s = __builtin_amdgcn_mfma_f32_16x16x32_f16(kf0, qfrag[qt][0], s, 0, 0, 0);
                sv[qt] = __builtin_amdgcn_mfma_f32_16x16x32_f16(kf1, qfrag[qt][1], s, 0, 0, 0);
            }
            __builtin_amdgcn_s_setprio(0);
            #pragma unroll
            for (int qt = 0; qt < 4; qt++) {
                const float p0 = exp2_fast(sv[qt][0]), p1 = exp2_fast(sv[qt][1]);
                const float p2 = exp2_fast(sv[qt][2]), p3 = exp2_fast(sv[qt][3]);
                lsum[qt] += (p0 + p1) + (p2 + p3);
                bfu[qt].x = __builtin_bit_cast(unsigned int, __builtin_amdgcn_cvt_pkrtz(p0, p1));
                bfu[qt].y = __builtin_bit_cast(unsigned int, __builtin_amdgcn_cvt_pkrtz(p2, p3));
            }
        }

        // ======== sub-iter 1: stage (T+1)'s half0, QK over keys 16..31 ====
        {
            if (T < 15) {
                ushort* vd = myL + 2048 + ((T + 1) & 1) * 2048;
                gload_lds16(kst0, myL);
                gload_lds16(kst1, myL + 512);
                gload_lds16(vstA, vd);
                gload_lds16(vstB, vd + 512);
                kst0 += 16 * E_; kst1 += 16 * E_; vstA += 1024; vstB += 1024;
                __builtin_amdgcn_s_waitcnt(0x0F74);   // vmcnt(4): half1 landed
            } else {
                __builtin_amdgcn_s_waitcnt(0x0F70);   // vmcnt(0): last landed
            }

            const ushort* kb = myL + 1024;            // K buf 1
            f16x8 kf0 = *(const f16x8*)&kb[c * 64 + ((qd ^ cs) * 8)];
            f16x8 kf1 = *(const f16x8*)&kb[c * 64 + (((4 + qd) ^ cs) * 8)];
            f32x4 sv[4];
            __builtin_amdgcn_s_setprio(1);
            #pragma unroll
            for (int qt = 0; qt < 4; qt++) {
                f32x4 s = {};
                s = __builtin_amdgcn_mfma_f32_16x16x32_f16(kf0, qfrag[qt][0], s, 0, 0, 0);
                sv[qt] = __builtin_amdgcn_mfma_f32_16x16x32_f16(kf1, qfrag[qt][1], s, 0, 0, 0);
            }
            __builtin_amdgcn_s_setprio(0);
            #pragma unroll
            for (int qt = 0; qt < 4; qt++) {
                const float p0 = exp2_fast(sv[qt][0]), p1 = exp2_fast(sv[qt][1]);
                const float p2 = exp2_fast(sv[qt][2]), p3 = exp2_fast(sv[qt][3]);
                lsum[qt] += (p0 + p1) + (p2 + p3);
                bfu[qt].z = __builtin_bit_cast(unsigned int, __builtin_amdgcn_cvt_pkrtz(p0, p1));
                bfu[qt].w = __builtin_bit_cast(unsigned int, __builtin_amdgcn_cvt_pkrtz(p2, p3));
            }
        }

        // ======== PV over the 32-key group: k=32 MFMA, pure-MFMA cluster ====
        const ushort* vb = myL + 2048 + (T & 1) * 2048;
        __builtin_amdgcn_s_setprio(1);
        #pragma unroll
        for (int dt = 0; dt < 4; dt++) {
            f16x8 vfr = *(const f16x8*)&vb[(dt * 16 + c) * 32 + vxo];
            #pragma unroll
            for (int qt = 0; qt < 4; qt++)
                acc[dt][qt] = __builtin_amdgcn_mfma_f32_16x16x32_f16(
                    vfr, __builtin_bit_cast(f16x8, bfu[qt]), acc[dt][qt], 0, 0, 0);
        }
        __builtin_amdgcn_s_setprio(0);
        // NO barrier: next iter only touches this wave's private region
    }

    __syncthreads();   // all waves done computing; LDS becomes reduce scratch

    // ---- cross-wave reduction (once per block) ----
    float* red = (float*)&L[0];        // 4 slots x 1024 floats = 16KB
    float* lsr = (float*)&L[8192];     // bytes 16K..17K: 4 waves x 64 queries

    #pragma unroll
    for (int qt = 0; qt < 4; qt++) {
        float v = lsum[qt];
        v += __shfl_xor(v, 16);
        v += __shfl_xor(v, 32);
        lsum[qt] = v;
    }
    if (lane < 16) {
        #pragma unroll
        for (int qt = 0; qt < 4; qt++) lsr[wv * 64 + qt * 16 + lane] = lsum[qt];
    }

    f32x4 own[4];                  // this wave owns d-tile dt == wv
    #pragma unroll
    for (int qt = 0; qt < 4; qt++)
        own[qt] = (wv == 0) ? acc[0][qt] : (wv == 1) ? acc[1][qt]
                : (wv == 2) ? acc[2][qt] : acc[3][qt];

    #pragma unroll
    for (int r = 1; r < 4; r++) {
        const int ds = (wv + r) & 3;          // distinct slots per wave
        #pragma unroll
        for (int qt = 0; qt < 4; qt++) {
            f32x4 sv = (ds == 0) ? acc[0][qt] : (ds == 1) ? acc[1][qt]
                     : (ds == 2) ? acc[2][qt] : acc[3][qt];
            *(f32x4*)&red[ds * 1024 + qt * 256 + lane * 4] = sv;
        }
        __syncthreads();
        #pragma unroll
        for (int qt = 0; qt < 4; qt++)
            own[qt] += *(const f32x4*)&red[wv * 1024 + qt * 256 + lane * 4];
        if (r < 3) __syncthreads();
    }

    float inv[4];
    #pragma unroll
    for (int qt = 0; qt < 4; qt++) {
        const int q = qt * 16 + c;
        inv[qt] = 1.0f / (lsr[q] + lsr[64 + q] + lsr[128 + q] + lsr[192 + q]);
    }

    // store: lane holds q = qt*16+c, d = wv*16 + qd*4 + (0..3); ctx unswizzled
    const size_t obase = qrow0 * E_ + h * 64 + wv * 16 + qd * 4;
    #pragma unroll
    for (int qt = 0; qt < 4; qt++) {
        f32x4 v = own[qt];
        const float iq = inv[qt];
        ushort4 o = make_ushort4(f2h(v[0] * iq), f2h(v[1] * iq),
                                 f2h(v[2] * iq), f2h(v[3] * iq));
        *(ushort4*)&ctxf[obase + (size_t)(qt * 16 + c) * E_] = o;
    }
}

// ---------------- launch ----------------
extern "C" void kernel_launch(void* const* d_in, const int* in_sizes, int n_in,
                              void* d_out, int out_size, void* d_ws, size_t ws_size,
                              hipStream_t stream)
{
    const float* x  = (const float*)d_in[0];
    const float* Wq = (const float*)d_in[1];
    const float* bq = (const float*)d_in[2];
    const float* Wk = (const float*)d_in[3];
    const float* bk = (const float*)d_in[4];
    const float* Wv = (const float*)d_in[5];
    const float* bv = (const float*)d_in[6];
    const float* Wo = (const float*)d_in[7];
    const float* bo = (const float*)d_in[8];
    float* out = (float*)d_out;

    // ws (ushort units): Qb|Kb|Vf|xf (4M each) | WT (4x1M) | ct|st (fp32)
    // alias: ctxf -> Qb (each attn block writes exactly the Q-tile region it
    // alone reads, after its last read — no cross-block hazard)
    ushort* Qb = (ushort*)d_ws;
    ushort* Kb = Qb + (size_t)M_ * E_;
    ushort* Vf = Kb + (size_t)M_ * E_;
    ushort* xf = Vf + (size_t)M_ * E_;
    ushort* WT = xf + (size_t)M_ * E_;
    float*  ct = (float*)(WT + (size_t)4 * E_ * E_);
    float*  st = ct + S_ * 32;
    ushort* ctxf = Qb;

    hipLaunchKernelGGL(prep_kernel, dim3(3328), dim3(256), 0, stream,
                       x, Wq, Wk, Wv, Wo, xf, WT, ct, st);

    // fused QKV: flat 256 blocks/mode (XCD-aware m-major), z = mode
    hipLaunchKernelGGL(gemm_f16, dim3(256, 1, 3), dim3(256), 0, stream,
                       xf, WT, bq, bk, bv, ct, st,
                       Qb, Kb, Vf);

    // attn: 1024 blocks (64 q-rows each), 3 blocks/CU
    hipLaunchKernelGGL(attn_mfma, dim3(B_ * H_ * (S_ / 64)), dim3(256), 0, stream,
                       Qb, Kb, Vf, ctxf);

    // output projection: 64x128 tiles, 512 blocks = 2/CU
    hipLaunchKernelGGL(gemm_proj, dim3(512), dim3(256), 0, stream,
                       ctxf, WT + (size_t)3 * E_ * E_, bo, out);
}